// Round 11
// baseline (83.343 us; speedup 1.0000x reference)
//
#include <hip/hip_runtime.h>
#include <hip/hip_bf16.h>

// SpectralConv2d: B=8, CIN=COUT=32, N=4096, modes 32x x 31y (u_ft needs y 0..15)
// r11: TLP fix. r10 counters: uft Occupancy 2.7% (1 wave/SIMD), VGPR 72 vs
// ~80 needed for in-flight loads -> serialized load batches, fully exposed
// latency. Re-tiled: uft grid 1024 (1 y/block, 7 prefetch loads/chunk,
// 24 KB LDS -> 4 blocks/CU); inv y-phases of 4 with double-buffered LDS
// (8 barriers vs 62). All layouts/swizzles/math r10-verified.
//
// ws (u32 slots), 18.0 MB:
//   E2in  [8][16][4096]           : 524288   (aliased by A32 after uft)
//   B_pre [8][64nt][64j][64n]     : 2097152
//   P     [8s][8b][16y][32c][64j] : 2097152 f32

#define NPTS 4096
#define TDIM 128
#define TWO_PI 6.283185307179586f

typedef __attribute__((ext_vector_type(8))) short bf16x8;
typedef __attribute__((ext_vector_type(4))) float f32x4;
typedef unsigned int u32;
typedef unsigned short u16;

__device__ __forceinline__ u32 pack2(float a, float b) {
  __hip_bfloat162 h = __float22bfloat162_rn(make_float2(a, b));  // v_cvt_pk_bf16_f32
  u32 r; __builtin_memcpy(&r, &h, 4); return r;
}
__device__ __forceinline__ float bflo(u32 u) { return __uint_as_float(u << 16); }
__device__ __forceinline__ float bfhi(u32 u) { return __uint_as_float(u & 0xFFFF0000u); }

// ---------------------------------------------------------------------------
// prep1 (r10 verbatim): E2in (y 0..15) + B_pre (conj(E1in)), linear layout.
__global__ __launch_bounds__(256) void prep1_kernel(
    const float* __restrict__ x_in, u32* __restrict__ E2in, u32* __restrict__ B_pre) {
  const int bid = blockIdx.x;              // 512
  const int b = bid & 7, ntile = bid >> 3; // 0..63
  const int tid = threadIdx.x;
  const int nl = tid & 63, task = tid >> 6;
  const int n = ntile * 64 + nl;
  float2 xv = *(const float2*)&x_in[(size_t)(b * NPTS + n) * 2];
  if (task < 2) {
    #pragma unroll
    for (int k = 0; k < 8; ++k) {
      int y = task * 8 + k;                          // 0..15 -> k2y = y
      float th = TWO_PI * xv.y * (float)y;
      float s, c; __sincosf(th, &s, &c);
      E2in[((b * 16 + y) << 12) + n] = pack2(c, s);
    }
  } else {
    u32* base = B_pre + (size_t)(b * 64 + ntile) * 4096;
    #pragma unroll
    for (int k = 0; k < 16; ++k) {
      int x = (task - 2) * 16 + k;
      float k1x = (x < 16) ? (float)x : (float)(x - 32);
      float th = TWO_PI * xv.x * k1x;
      float s, c; __sincosf(th, &s, &c);
      base[(2 * x) * 64 + nl]     = pack2(c, s);     // conj(e1) re-row
      base[(2 * x + 1) * 64 + nl] = pack2(-s, c);    // conj(e1) im-row
    }
  }
}

// ---------------------------------------------------------------------------
// uft: grid 1024 = (b8, s8, y16). One y per block; 8 chunks of 64 n (K=128).
// Prefetch 7x16B/chunk into regs -> pack -> swizzled LDS -> MFMA.
// LDS 24 KB, ~80 VGPR -> 4 blocks/CU, 4 waves/SIMD.
__global__ __launch_bounds__(256) void uft_kernel(
    const float* __restrict__ u, const u32* __restrict__ E2in,
    const u32* __restrict__ B_pre, float* __restrict__ P) {
  const int bid = blockIdx.x;
  const int b = bid & 7;                   // XCD pin
  const int rest = bid >> 3;               // 0..127
  const int s = rest & 7;
  const int y = rest >> 3;                 // 0..15
  const int tid = threadIdx.x;
  const int lane = tid & 63, jt = tid >> 6;
  const int colw = lane & 15, kq = lane >> 4;

  __shared__ __align__(16) u16 As[32 * 128];   // 8 KB: rows c, 256B, swizzled
  __shared__ __align__(16) u16 Bs[64 * 128];   // 16 KB: rows j, 256B, swizzled

  const int cseg = tid & 15;               // 16B segment within a row
  const int crow = tid >> 4;               // 0..15 (A: c rows crow, crow+16; B: j)

  f32x4 acc0 = {0.f, 0.f, 0.f, 0.f}, acc1 = {0.f, 0.f, 0.f, 0.f};

  float4 pu[2]; uint4 pe; uint4 pb[4];
  auto load_regs = [&](int ch) {
    const int n0 = s * 512 + ch * 64;
    const int nt = s * 8 + ch;
    #pragma unroll
    for (int i = 0; i < 2; ++i)
      pu[i] = *(const float4*)&u[(size_t)(b * 32 + crow + i * 16) * NPTS + n0 + cseg * 4];
    pe = *(const uint4*)&E2in[((b * 16 + y) << 12) + n0 + cseg * 4];
    #pragma unroll
    for (int i = 0; i < 4; ++i)
      pb[i] = *(const uint4*)&B_pre[(size_t)(b * 64 + nt) * 4096 + (crow + i * 16) * 64 + cseg * 4];
  };
  load_regs(0);

  for (int ch = 0; ch < 8; ++ch) {
    __syncthreads();   // previous chunk's MFMA reads done

    // build A = u .* conj(E2_y), stage swizzled
    {
      const u32 ee[4] = {pe.x, pe.y, pe.z, pe.w};
      #pragma unroll
      for (int i = 0; i < 2; ++i) {
        const int c = crow + i * 16;
        const float uu[4] = {pu[i].x, pu[i].y, pu[i].z, pu[i].w};
        uint4 w;
        u32* wp = &w.x;
        #pragma unroll
        for (int p2 = 0; p2 < 4; ++p2)
          wp[p2] = pack2(uu[p2] * bflo(ee[p2]), -(uu[p2] * bfhi(ee[p2])));
        *(uint4*)((char*)As + c * 256 + ((cseg * 16) ^ ((c & 7) << 4))) = w;
      }
    }
    // stage B chunk swizzled
    #pragma unroll
    for (int i = 0; i < 4; ++i) {
      const int j = crow + i * 16;
      *(uint4*)((char*)Bs + j * 256 + ((cseg * 16) ^ ((j & 7) << 4))) = pb[i];
    }
    if (ch < 7) load_regs(ch + 1);   // overlap barrier + MFMA
    __syncthreads();

    const int swz = (colw & 7) << 4;
    #pragma unroll
    for (int ks = 0; ks < 4; ++ks) {
      const int kb = ks * 64 + kq * 16;
      bf16x8 fb = *(bf16x8*)((char*)Bs + (jt * 16 + colw) * 256 + (kb ^ swz));
      bf16x8 a0 = *(bf16x8*)((char*)As + colw * 256 + (kb ^ swz));
      bf16x8 a1 = *(bf16x8*)((char*)As + (16 + colw) * 256 + (kb ^ swz));
      acc0 = __builtin_amdgcn_mfma_f32_16x16x32_bf16(a0, fb, acc0, 0, 0, 0);
      acc1 = __builtin_amdgcn_mfma_f32_16x16x32_bf16(a1, fb, acc1, 0, 0, 0);
    }
  }

  // P[s][b][y][c][j]: D row = kq*4+r (c in m-tile), col = colw (j in j-tile jt)
  size_t base = (((size_t)s * 8 + b) * 16 + y) * 2048;
  #pragma unroll
  for (int r = 0; r < 4; ++r) {
    P[base + (kq * 4 + r) * 64 + jt * 16 + colw] = acc0[r];
    P[base + (16 + kq * 4 + r) * 64 + jt * 16 + colw] = acc1[r];
  }
}

// ---------------------------------------------------------------------------
// apply (r10 verbatim): 8-way split-K reduce + emb + Hermitian ext; writes
// bf16-packed A32[b][y0..30][c][j=2X+comp].
__global__ __launch_bounds__(512) void apply_kernel(
    const float* __restrict__ t, const float* __restrict__ w_freq,
    const float* __restrict__ b_freq, const float* __restrict__ w1,
    const float* __restrict__ w2, const float* __restrict__ P,
    u32* __restrict__ A32) {
  const int x = blockIdx.x, b = blockIdx.y;
  const int tid = threadIdx.x;
  const int m1 = x & 15, sel = x >> 4;

  __shared__ float uf_s[32][16][2];
  __shared__ float emb_s[16][2];
  __shared__ float part[512];

  for (int e = tid; e < 1024; e += 512) {
    int i = e >> 5, r = e & 31, yy = r >> 1, comp = r & 1;
    size_t base = (((size_t)(b * 16 + yy)) * 32 + i) * 64 + 2 * x + comp;
    float sacc = 0.f;
    #pragma unroll
    for (int ss = 0; ss < 8; ++ss) sacc += P[base + (size_t)ss * 262144];
    uf_s[i][yy][comp] = sacc;
  }
  {
    int jjl = tid & 31, kc = tid >> 5;           // kc 0..15
    int yy = jjl >> 1, pp = jjl & 1;
    int jj = ((m1 * 16 + yy) * 2 + sel) * 2 + pp;
    float sv = 0.f;
    #pragma unroll
    for (int k2 = 0; k2 < 8; ++k2) {
      int k = kc * 8 + k2;
      sv += t[b * TDIM + k] * w_freq[k * 1024 + jj];
    }
    part[tid] = sv;
  }
  __syncthreads();
  if (tid < 32) {
    int yy = tid >> 1, pp = tid & 1;
    int jj = ((m1 * 16 + yy) * 2 + sel) * 2 + pp;
    float acc = b_freq[jj];
    #pragma unroll
    for (int c2 = 0; c2 < 16; ++c2) acc += part[c2 * 32 + tid];
    emb_s[yy][pp] = acc;
  }
  __syncthreads();

  int o = tid >> 4, y = tid & 15;
  const float* wsel = sel ? w2 : w1;
  float fr = 0.f, fi = 0.f;
  #pragma unroll 4
  for (int i = 0; i < 32; ++i) {
    float2 w = *(const float2*)&wsel[(size_t)(((i * 32 + o) * 16 + m1) * 16 + y) * 2];
    float ur = uf_s[i][y][0], ui = uf_s[i][y][1];
    fr += ur * w.x - ui * w.y;
    fi += ur * w.y + ui * w.x;
  }
  float er = emb_s[y][0], ei = emb_s[y][1];
  float orr = fr * er - fi * ei;
  float oii = fr * ei + fi * er;
  A32[((b * 31 + y) * 32 + o) * 32 + x] = pack2(orr, oii);
  if (y > 0)
    A32[((b * 31 + (31 - y)) * 32 + o) * 32 + (31 - x)] = pack2(orr, -oii);
}

// ---------------------------------------------------------------------------
// inv: grid 1024 = (b, nt64, h2). Bg/e2s prologue (r10 verbatim). y handled in
// 8 phases of 4 (last 3) with double-buffered A-stage: 1 barrier/phase.
__global__ __launch_bounds__(256) void inv_kernel(
    const u32* __restrict__ A32, const float* __restrict__ x_out,
    float* __restrict__ Y) {
  const int bid = blockIdx.x;
  const int b = bid & 7;
  const int rest = bid >> 3;               // 0..127
  const int nt = rest & 63;
  const int h = rest >> 6;                 // c-half 0/1
  const int n0 = nt * 64;
  const int tid = threadIdx.x;
  const int lane = tid & 63, wv = tid >> 6;
  const int colw = lane & 15, kq = lane >> 4;

  __shared__ __align__(16) u16 Bgr[64 * 64];       // [n][k=2X+comp], swizzled
  __shared__ __align__(16) u16 Bgi[64 * 64];
  __shared__ u32 e2s[31 * 64];
  __shared__ __align__(16) u16 Asl[2][4 * 16 * 64]; // dbuf: rows yl*16+cl, 128B

  {
    const int n = tid & 63, Xg = tid >> 6;
    float x0 = x_out[(size_t)(b * NPTS + n0 + n) * 2];
    #pragma unroll
    for (int i = 0; i < 8; ++i) {
      int X = Xg * 8 + i;
      float k1x = (X < 16) ? (float)X : (float)(X - 32);
      float th = TWO_PI * x0 * k1x;
      float s1, c1; __sincosf(th, &s1, &c1);
      int byt = (4 * X) ^ ((n & 7) << 4);
      *(u32*)((char*)Bgr + n * 128 + byt) = pack2(c1, -s1);
      *(u32*)((char*)Bgi + n * 128 + byt) = pack2(s1, c1);
    }
  }
  {
    const int n = tid & 63;
    float x1 = x_out[(size_t)(b * NPTS + n0 + n) * 2 + 1];
    for (int idx = tid; idx < 1984; idx += 256) {
      int y = idx >> 6;
      float k2y = (y < 16) ? (float)y : (float)(y - 31);
      float th = TWO_PI * x1 * k2y;
      float s2, c2; __sincosf(th, &s2, &c2);
      e2s[idx] = pack2(c2, s2);
    }
  }

  // A-stage task mapping: 2 uint4/thread cover 4y x 2KB
  const u32* Abase = A32 + (size_t)b * 31 * 1024 + h * 512;  // + y*1024 + cl*32 + seg*4
  const int syl0 = tid >> 7;               // i=0: yl of first task
  const int scl = (tid >> 3) & 15, sseg = tid & 7;
  uint4 pA[2];
  auto loadA = [&](int y0) {
    #pragma unroll
    for (int i = 0; i < 2; ++i) {
      int yy = y0 + syl0 + i * 2;
      pA[i] = (yy < 31) ? *(const uint4*)(Abase + yy * 1024 + scl * 32 + sseg * 4)
                        : make_uint4(0u, 0u, 0u, 0u);
    }
  };
  loadA(0);
  __syncthreads();   // Bg/e2s ready

  const int brow = wv * 16 + colw;
  bf16x8 bgr[2], bgi[2];
  #pragma unroll
  for (int ks = 0; ks < 2; ++ks) {
    int kb = ks * 64 + kq * 16;
    bgr[ks] = *(bf16x8*)((char*)Bgr + brow * 128 + (kb ^ ((brow & 7) << 4)));
    bgi[ks] = *(bf16x8*)((char*)Bgi + brow * 128 + (kb ^ ((brow & 7) << 4)));
  }

  f32x4 Yh = {0.f, 0.f, 0.f, 0.f};
  const int swz = (colw & 7) << 4;

  #pragma unroll 1
  for (int p = 0; p < 8; ++p) {
    const int y0 = p * 4;
    // stage this phase's 4 y's from prefetch regs
    char* buf = (char*)Asl[p & 1];
    #pragma unroll
    for (int i = 0; i < 2; ++i) {
      int yl = syl0 + i * 2;
      *(uint4*)(buf + (yl * 16 + scl) * 128 + ((sseg * 16) ^ ((scl & 7) << 4))) = pA[i];
    }
    __syncthreads();   // stage visible (dbuf: prev phase's buffer untouched)
    if (p < 7) loadA(y0 + 4);   // prefetch next phase (overlaps MFMA)

    const int ny = (p < 7) ? 4 : 3;
    for (int yl = 0; yl < ny; ++yl) {
      bf16x8 af0 = *(bf16x8*)(buf + (yl * 16 + colw) * 128 + ((kq * 16) ^ swz));
      bf16x8 af1 = *(bf16x8*)(buf + (yl * 16 + colw) * 128 + ((64 + kq * 16) ^ swz));
      f32x4 z = {0.f, 0.f, 0.f, 0.f};
      f32x4 gr = __builtin_amdgcn_mfma_f32_16x16x32_bf16(af0, bgr[0], z, 0, 0, 0);
      gr = __builtin_amdgcn_mfma_f32_16x16x32_bf16(af1, bgr[1], gr, 0, 0, 0);
      f32x4 gi = __builtin_amdgcn_mfma_f32_16x16x32_bf16(af0, bgi[0], z, 0, 0, 0);
      gi = __builtin_amdgcn_mfma_f32_16x16x32_bf16(af1, bgi[1], gi, 0, 0, 0);
      u32 e2 = e2s[(y0 + yl) * 64 + brow];
      float c2 = bflo(e2), s2 = bfhi(e2);
      #pragma unroll
      for (int r = 0; r < 4; ++r) Yh[r] += gr[r] * c2 - gi[r] * s2;
    }
  }

  int n = n0 + brow;
  #pragma unroll
  for (int r = 0; r < 4; ++r)
    Y[(size_t)(b * 32 + kq * 4 + r + 16 * h) * NPTS + n] = Yh[r];
}

// ---------------------------------------------------------------------------
extern "C" void kernel_launch(void* const* d_in, const int* in_sizes, int n_in,
                              void* d_out, int out_size, void* d_ws, size_t ws_size,
                              hipStream_t stream) {
  const float* u      = (const float*)d_in[0];
  const float* x_in   = (const float*)d_in[1];
  const float* x_out  = (const float*)d_in[2];
  const float* t      = (const float*)d_in[3];
  const float* w_freq = (const float*)d_in[4];
  const float* b_freq = (const float*)d_in[5];
  const float* w1     = (const float*)d_in[6];
  const float* w2     = (const float*)d_in[7];
  float* Y = (float*)d_out;

  u32* E2in  = (u32*)d_ws;                 // 524288
  u32* B_pre = E2in + 524288;              // 2097152
  float* P   = (float*)(B_pre + 2097152);  // 2097152 f32
  u32* A32   = E2in;                       // alias: E2in dead after uft

  prep1_kernel<<<512, 256, 0, stream>>>(x_in, E2in, B_pre);
  uft_kernel<<<1024, 256, 0, stream>>>(u, E2in, B_pre, P);
  apply_kernel<<<dim3(32, 8), 512, 0, stream>>>(t, w_freq, b_freq, w1, w2, P, A32);
  inv_kernel<<<1024, 256, 0, stream>>>(A32, x_out, Y);
}